// Round 1
// baseline (651.060 us; speedup 1.0000x reference)
//
#include <hip/hip_runtime.h>

// Shapes (fixed by setup_inputs): B=16, C=512, h=w=16 (P=256), E=128, N=32, H=W=512.
#define BB  16
#define CC  512
#define EE  128
#define NN  32
#define HI  512
#define WI  512
#define P   256   // h*w = 16*16

// Kernel A: proj[b,e,p] = relu( (sum_c conv_w[e,c]*features[b,c,p] + conv_b[e]) * sc[e] + sh[e] )
// grid (16 b, 16 e-tiles of 8), 256 threads = p. conv_w index is wave-uniform -> s_load.
__global__ __launch_bounds__(256) void proj_kernel(
    const float* __restrict__ features, const float* __restrict__ conv_w,
    const float* __restrict__ conv_b,  const float* __restrict__ bn_gamma,
    const float* __restrict__ bn_beta, const float* __restrict__ bn_mean,
    const float* __restrict__ bn_var,  float* __restrict__ proj) {
  const int b  = blockIdx.x;
  const int e0 = blockIdx.y * 8;
  const int p  = threadIdx.x;

  float acc[8];
#pragma unroll
  for (int i = 0; i < 8; ++i) acc[i] = 0.f;

  const float* fb = features + (size_t)b * CC * P + p;
#pragma unroll 8
  for (int c = 0; c < CC; ++c) {
    float f = fb[(size_t)c * P];
#pragma unroll
    for (int i = 0; i < 8; ++i)
      acc[i] = fmaf(conv_w[(e0 + i) * CC + c], f, acc[i]);
  }

#pragma unroll
  for (int i = 0; i < 8; ++i) {
    const int e = e0 + i;
    const float sc = bn_gamma[e] / sqrtf(bn_var[e] + 1e-5f);
    const float sh = bn_beta[e] - bn_mean[e] * sc;
    float r = fmaf(acc[i] + conv_b[e], sc, sh);
    proj[((size_t)b * EE + e) * P + p] = fmaxf(r, 0.f);
  }
}

// Kernel B: per (b,n) block: 4-tap bilinear gather -> mr (LDS) -> sum -> obj -> MLP -> out.
__global__ __launch_bounds__(256) void pool_mlp_kernel(
    const float* __restrict__ masks, const float* __restrict__ proj,
    const float* __restrict__ w1, const float* __restrict__ b1,
    const float* __restrict__ w2, const float* __restrict__ b2,
    float* __restrict__ out) {
  __shared__ float mr_s[P];
  __shared__ float wsum[4];
  __shared__ float obj_s[EE];
  __shared__ float hdn_s[EE];

  const int bn = blockIdx.x;        // b*32 + n
  const int b  = bn >> 5;
  const int t  = threadIdx.x;
  const int o  = t >> 4;            // output row 0..15
  const int q  = t & 15;            // output col 0..15

  // bilinear: src = 32*i + 15.5 -> taps at 32i+15, 32i+16 with weight 0.5 each dim
  const float* mb = masks + (size_t)bn * HI * WI;
  const size_t r0 = (size_t)(32 * o + 15) * WI;
  const int    c0 = 32 * q + 15;
  const float v = 0.25f * (mb[r0 + c0] + mb[r0 + c0 + 1] +
                           mb[r0 + WI + c0] + mb[r0 + WI + c0 + 1]);
  mr_s[t] = v;

  // block-reduce sum of mr
  float s = v;
#pragma unroll
  for (int off = 32; off > 0; off >>= 1) s += __shfl_down(s, off, 64);
  if ((t & 63) == 0) wsum[t >> 6] = s;
  __syncthreads();
  const float inv = 1.f / (wsum[0] + wsum[1] + wsum[2] + wsum[3] + 1e-8f);

  // obj[e] = (sum_p proj[b,e,p] * mr[p]) * inv   (threads 0..127 own e)
  if (t < EE) {
    const float4* pr4 = (const float4*)(proj + ((size_t)b * EE + t) * P);
    const float4* mr4 = (const float4*)mr_s;
    float acc = 0.f;
#pragma unroll 8
    for (int i = 0; i < P / 4; ++i) {
      const float4 a = pr4[i], m = mr4[i];
      acc = fmaf(a.x, m.x, acc); acc = fmaf(a.y, m.y, acc);
      acc = fmaf(a.z, m.z, acc); acc = fmaf(a.w, m.w, acc);
    }
    obj_s[t] = acc * inv;
  }
  __syncthreads();

  // hdn[j] = relu(obj . w1[j,:] + b1[j])
  if (t < EE) {
    const float4* wr = (const float4*)(w1 + (size_t)t * EE);
    const float4* ob = (const float4*)obj_s;
    float acc = b1[t];
#pragma unroll 8
    for (int i = 0; i < EE / 4; ++i) {
      const float4 a = wr[i], m = ob[i];
      acc = fmaf(a.x, m.x, acc); acc = fmaf(a.y, m.y, acc);
      acc = fmaf(a.z, m.z, acc); acc = fmaf(a.w, m.w, acc);
    }
    hdn_s[t] = fmaxf(acc, 0.f);
  }
  __syncthreads();

  // out[k] = hdn . w2[k,:] + b2[k]
  if (t < EE) {
    const float4* wr = (const float4*)(w2 + (size_t)t * EE);
    const float4* hd = (const float4*)hdn_s;
    float acc = b2[t];
#pragma unroll 8
    for (int i = 0; i < EE / 4; ++i) {
      const float4 a = wr[i], m = hd[i];
      acc = fmaf(a.x, m.x, acc); acc = fmaf(a.y, m.y, acc);
      acc = fmaf(a.z, m.z, acc); acc = fmaf(a.w, m.w, acc);
    }
    out[(size_t)bn * EE + t] = acc;
  }
}

extern "C" void kernel_launch(void* const* d_in, const int* in_sizes, int n_in,
                              void* d_out, int out_size, void* d_ws, size_t ws_size,
                              hipStream_t stream) {
  const float* features = (const float*)d_in[0];
  const float* masks    = (const float*)d_in[1];
  const float* conv_w   = (const float*)d_in[2];
  const float* conv_b   = (const float*)d_in[3];
  const float* bn_gamma = (const float*)d_in[4];
  const float* bn_beta  = (const float*)d_in[5];
  const float* bn_mean  = (const float*)d_in[6];
  const float* bn_var   = (const float*)d_in[7];
  const float* w1       = (const float*)d_in[8];
  const float* b1       = (const float*)d_in[9];
  const float* w2       = (const float*)d_in[10];
  const float* b2       = (const float*)d_in[11];
  float* out  = (float*)d_out;
  float* proj = (float*)d_ws;   // 16*128*256 floats = 2 MB

  proj_kernel<<<dim3(BB, EE / 8), 256, 0, stream>>>(
      features, conv_w, conv_b, bn_gamma, bn_beta, bn_mean, bn_var, proj);
  pool_mlp_kernel<<<BB * NN, 256, 0, stream>>>(masks, proj, w1, b1, w2, b2, out);
}